// Round 4
// baseline (189.122 us; speedup 1.0000x reference)
//
#include <hip/hip_runtime.h>

// MeanConv: out = mask * (1/7) * sum_{k in 3,5,..,15} boxmean_k(x), edge padding.
// Per-tile 2D integral image in LDS; each box sum = 4-corner difference.
//   P1: stage+row-prefix fused (float4 global loads, 4-lane shfl fixup).
//   P2: column prefix, 4 row-segments per column, register prefix + shfl fixup.
//   P3: 16 px/thread. Per scale, read BOTH corner rows as ALIGNED float4
//       windows (ds_read_b128): PSTR=84 keeps every row 16B-aligned and
//       CS=(8-p)&~3 aligns the window start. 98 b128/thread vs ~175
//       ds_read2_b32 — LDS unit is access-limited (~12cy/b128 vs ~11.6cy
//       per read2 pair, m134), so this is ~-40% LDS cycles in phase 3.
// Only 2 barriers. LDS 27.2 KB.

#define TILE   64
#define HALO   7
#define LHX    8            // left halo (8 for float4 alignment)
#define NCOL   80           // staged cols: c0-8 .. c0+71
#define NROW   78           // staged rows: r0-7 .. r0+70
#define PSTR   84           // multiple of 4: rows 16B-aligned; 21 odd -> b128 conflict-free
#define PROWSA 81           // rows 0..78 used + 2 slack (safe predicated reads)
#define HH     4096
#define WW     4096

__global__ __launch_bounds__(256) void meanconv_kernel(
    const float* __restrict__ x, const float* __restrict__ mask,
    float* __restrict__ out)
{
    __shared__ float P[PROWSA * PSTR];   // 81*84*4 = 27216 B
    const int tid = threadIdx.x;
    const int c0  = blockIdx.x * TILE;
    const int r0  = blockIdx.y * TILE;

    // zero row 0 (cols 0..80); rows 1..78 written below, no race
    if (tid < 81) P[tid] = 0.0f;

    const bool xint = (c0 >= LHX) && (c0 - LHX + NCOL <= WW);

    // ---- phase 1: fused global stage + row-wise inclusive prefix ----
    for (int idx = tid; idx < NROW * 4; idx += 256) {
        const int lr  = idx >> 2;        // staged row 0..77
        const int s   = idx & 3;         // 20-col segment within the row
        const int gr  = min(max(r0 + lr - HALO, 0), HH - 1);
        const int gc0 = c0 - LHX + 20 * s;
        float v[20];
        if (xint) {
            const float* src = &x[(size_t)gr * WW + gc0];
            #pragma unroll
            for (int q = 0; q < 5; ++q) {
                const float4 t = *(const float4*)(src + 4 * q);
                v[4*q+0] = t.x; v[4*q+1] = t.y; v[4*q+2] = t.z; v[4*q+3] = t.w;
            }
        } else {
            #pragma unroll
            for (int i = 0; i < 20; ++i) {
                const int gc = min(max(gc0 + i, 0), WW - 1);
                v[i] = x[(size_t)gr * WW + gc];
            }
        }
        #pragma unroll
        for (int i = 1; i < 20; ++i) v[i] += v[i - 1];
        // 4-lane (one row) exclusive prefix of segment totals
        const float tot = v[19];
        float sum = tot;
        float u = __shfl_up(sum, 1, 4); if (s >= 1) sum += u;
        u       = __shfl_up(sum, 2, 4); if (s >= 2) sum += u;
        const float off = sum - tot;
        float* dst = &P[(lr + 1) * PSTR + 1 + 20 * s];
        #pragma unroll
        for (int i = 0; i < 20; ++i) dst[i] = v[i] + off;
    }
    __syncthreads();

    // ---- phase 2: column-wise inclusive prefix over rows 1..78 ----
    for (int idx = tid; idx < 80 * 4; idx += 256) {
        const int c  = (idx >> 2) + 1;   // col 1..80
        const int s  = idx & 3;          // row segment (20,20,20,18)
        const int rs = 1 + 20 * s;
        float v[20];
        float run = 0.0f;
        #pragma unroll
        for (int i = 0; i < 20; ++i) {
            const int r = rs + i;
            float t = P[r * PSTR + c];   // rows 79,80 are in-bounds slack
            t = (r < 79) ? t : 0.0f;     // zero out slack garbage
            run += t; v[i] = run;
        }
        const float tot = run;
        float sum = tot;
        float u = __shfl_up(sum, 1, 4); if (s >= 1) sum += u;
        u       = __shfl_up(sum, 2, 4); if (s >= 2) sum += u;
        const float off = sum - tot;
        #pragma unroll
        for (int i = 0; i < 20; ++i) {
            const int r = rs + i;
            if (r < 79) P[r * PSTR + c] = v[i] + off;
        }
    }
    __syncthreads();
    // P[a][b] = sum of staged[row < a][col < b].

    // ---- phase 3: 16 consecutive-x pixels per thread, one row each ----
    // thread (g, ty): g = column group (4 groups of 16 px), ty = tile row.
    // Per scale p: aligned float4 window covering cols [B0+CS, B0+CS+4*NR)
    // of both corner rows; D = rB - rT; a[i] += w*(D[o+k+i] - D[o+i]).
    const int g  = tid & 3;
    const int ty = tid >> 2;             // 0..63
    const int B0 = 16 * g;
    const int A  = ty + HALO;            // staged row of the pixel
    float a[16];
    #pragma unroll
    for (int i = 0; i < 16; ++i) a[i] = 0.0f;

    #pragma unroll
    for (int p = 1; p <= 7; ++p) {
        const int   k  = 2 * p + 1;
        const float w  = 1.0f / (7.0f * (float)(k * k));
        const int   CS = (8 - p) & ~3;           // 4 (p<=4) or 0 (p>=5)
        const int   NR = (25 + p - CS + 3) >> 2; // float4s: 6,6,6,7,8,8,8
        const int   o  = 8 - p - CS;             // col (8-p) offset in window
        const float* rT = &P[(A - p)     * PSTR + B0 + CS];
        const float* rB = &P[(A + p + 1) * PSTR + B0 + CS];
        float D[32];
        #pragma unroll
        for (int q = 0; q < NR; ++q) {
            const float4 tq = *(const float4*)(rT + 4 * q);
            const float4 bq = *(const float4*)(rB + 4 * q);
            D[4*q+0] = bq.x - tq.x;
            D[4*q+1] = bq.y - tq.y;
            D[4*q+2] = bq.z - tq.z;
            D[4*q+3] = bq.w - tq.w;
        }
        #pragma unroll
        for (int i = 0; i < 16; ++i)
            a[i] += w * (D[o + k + i] - D[o + i]);
    }

    const int gr = r0 + ty, gc = c0 + B0;
    const float* mrow = &mask[(size_t)gr * WW + gc];
    float*       orow = &out[(size_t)gr * WW + gc];
    #pragma unroll
    for (int q = 0; q < 4; ++q) {
        const float4 m = *(const float4*)(mrow + 4 * q);
        float4 o4;
        o4.x = a[4*q+0] * m.x;
        o4.y = a[4*q+1] * m.y;
        o4.z = a[4*q+2] * m.z;
        o4.w = a[4*q+3] * m.w;
        *(float4*)(orow + 4 * q) = o4;
    }
}

extern "C" void kernel_launch(void* const* d_in, const int* in_sizes, int n_in,
                              void* d_out, int out_size, void* d_ws, size_t ws_size,
                              hipStream_t stream) {
    const float* x    = (const float*)d_in[0];
    const float* mask = (const float*)d_in[1];
    float*       out  = (float*)d_out;
    dim3 grid(WW / TILE, HH / TILE);
    meanconv_kernel<<<grid, 256, 0, stream>>>(x, mask, out);
}